// Round 14
// baseline (425.336 us; speedup 1.0000x reference)
//
#include <hip/hip_runtime.h>

#define D 256          // D_IN == D_OUT == 256
#define BSHIFT 7       // 128 rows per coarse bucket
#define BROWS 128
#define CHUNK 8192     // edges per bucket_hist / bucket_scatter block
// NB = ceil(100000/128) = 782; kernels assume NB <= 1024

typedef __attribute__((ext_vector_type(8))) short bf16x8;  // 8 bf16 in 4 VGPRs
typedef __attribute__((ext_vector_type(4))) float f32x4;
typedef __attribute__((ext_vector_type(4))) int   i32x4;

__device__ inline ushort f2bf_rne(float f) {  // fp32 -> bf16, round-to-nearest-even
    uint u = __builtin_bit_cast(uint, f);
    return (ushort)((u + 0x7FFFu + ((u >> 16) & 1u)) >> 16);
}

// ===========================================================================
// prep: conv_wt (wt[n][k] = bf16(W[k][n])) + zero bcnt, fused by idx range
// ===========================================================================
__global__ __launch_bounds__(256) void prep(const float* __restrict__ w,
                                            ushort* __restrict__ wt,
                                            int* __restrict__ bcnt, int NB) {
    const int idx = blockIdx.x * 256 + threadIdx.x;
    if (idx < D * D) {
        const int n = idx >> 8, k = idx & 255;
        wt[n * 256 + k] = f2bf_rne(w[k * 256 + n]);
    } else if (idx - D * D < NB) {
        bcnt[idx - D * D] = 0;
    }
}

// ===========================================================================
// Bucket-level histogram.  edge_row loads nt: read-once stream here (L2 will
// have evicted it before gemm_scatter re-reads), keep MALL space for sup.
// ===========================================================================
__global__ __launch_bounds__(256) void bucket_hist(const int* __restrict__ edge_row,
                                                   int* __restrict__ bcnt,
                                                   int E, int NB) {
    __shared__ int bh[1024];
    const int tid = threadIdx.x;
    for (int i = tid; i < 1024; i += 256) bh[i] = 0;
    __syncthreads();

    const int e0 = blockIdx.x * CHUNK;
    const int e1 = min(e0 + CHUNK, E);
    for (int i = e0 + tid * 4; i < e1; i += 1024) {
        if (i + 3 < e1) {
            const i32x4 r = __builtin_nontemporal_load((const i32x4*)(edge_row + i));
            atomicAdd(&bh[r[0] >> BSHIFT], 1);
            atomicAdd(&bh[r[1] >> BSHIFT], 1);
            atomicAdd(&bh[r[2] >> BSHIFT], 1);
            atomicAdd(&bh[r[3] >> BSHIFT], 1);
        } else {
            for (int j = i; j < e1; ++j) atomicAdd(&bh[edge_row[j] >> BSHIFT], 1);
        }
    }
    __syncthreads();

    for (int b = tid; b < NB; b += 256) {
        const int c = bh[b];
        if (c) atomicAdd(&bcnt[b], c);
    }
}

// ===========================================================================
// Single-block exclusive scan over NB <= 2048 bucket counts.
// bstart (prefix), bcursor (mutable copy), bstart[NB] = E, row_start[N] = E.
// ===========================================================================
__global__ __launch_bounds__(512) void bucket_scan(const int* __restrict__ bcnt,
                                                   int* __restrict__ bstart,
                                                   int* __restrict__ bcursor,
                                                   int* __restrict__ row_start,
                                                   int NB, int N, int E) {
    __shared__ int psum[512];
    const int tid = threadIdx.x;
    int v[4];
    int s = 0;
#pragma unroll
    for (int k = 0; k < 4; ++k) {
        const int i = tid * 4 + k;
        v[k] = (i < NB) ? bcnt[i] : 0;
        s += v[k];
    }
    psum[tid] = s;
    __syncthreads();
#pragma unroll
    for (int off = 1; off < 512; off <<= 1) {
        const int t = (tid >= off) ? psum[tid - off] : 0;
        __syncthreads();
        psum[tid] += t;
        __syncthreads();
    }
    int run = psum[tid] - s;  // exclusive prefix of this thread's 4-group
#pragma unroll
    for (int k = 0; k < 4; ++k) {
        const int i = tid * 4 + k;
        if (i < NB) { bstart[i] = run; bcursor[i] = run; }
        run += v[k];
    }
    if (tid == 0) { bstart[NB] = E; row_start[N] = E; }
}

// ===========================================================================
// gemm_scatter: gemm + bucket scatter, interleaved roles (proven r12).
// x staged with nt loads (read-once 102 MB stream); edge_col/val nt
// (read-once); edge_row plain in phase 1 (re-read in phase 3, L2-hot).
// ===========================================================================
union SMemGS {
    ushort As[64 * 256];  // 32 KB
    int    cur[1024];
};

__global__ __launch_bounds__(256) void gemm_scatter(
        const float* __restrict__ x, const ushort* __restrict__ wt,
        ushort* __restrict__ sup, int N, int ngemm,
        const int* __restrict__ edge_row, const int* __restrict__ edge_col,
        const float* __restrict__ edge_val, int* __restrict__ bcursor,
        unsigned long long* __restrict__ ebuck, int E, int NB, int nchunk) {
    __shared__ SMemGS sm;
    const int tid = threadIdx.x;
    const int bid = blockIdx.x;

    const bool is_scatter = ((bid % 5) == 4) && (bid / 5 < nchunk);

    if (!is_scatter) {
        // ---------------- GEMM ----------------
        const int gb = bid - (bid + 1) / 5;  // gemm block index
        if (gb >= ngemm) return;
        const int wv  = tid >> 6;
        const int ln  = tid & 63;
        const int row0 = gb * 64;

        for (int i = tid; i < 64 * 64; i += 256) {
            const int r = i >> 6, c = i & 63;
            int gr = row0 + r;
            if (gr >= N) gr = N - 1;
            const f32x4 xv =
                __builtin_nontemporal_load((const f32x4*)(x + (size_t)gr * D + c * 4));
            ushort4 b;
            b.x = f2bf_rne(xv[0]); b.y = f2bf_rne(xv[1]);
            b.z = f2bf_rne(xv[2]); b.w = f2bf_rne(xv[3]);
            const int byte = (r * 512 + c * 8) ^ ((r & 7) << 4);
            *(ushort4*)((char*)sm.As + byte) = b;
        }
        __syncthreads();

        f32x4 acc[16];
#pragma unroll
        for (int n = 0; n < 16; ++n) acc[n] = (f32x4){0.f, 0.f, 0.f, 0.f};

        const int arow = wv * 16 + (ln & 15);
        const int ksub = (ln >> 4) * 16;
        const ushort* wbase = wt + (ln & 15) * 256;

#pragma unroll
        for (int kk = 0; kk < 8; ++kk) {
            const int abyte = (arow * 512 + kk * 64 + ksub) ^ ((arow & 7) << 4);
            const bf16x8 af = *(const bf16x8*)((const char*)sm.As + abyte);
            const ushort* wp = wbase + kk * 32 + (ln >> 4) * 8;
#pragma unroll
            for (int n = 0; n < 16; ++n) {
                const bf16x8 bf = *(const bf16x8*)(wp + n * 16 * 256);
                acc[n] = __builtin_amdgcn_mfma_f32_16x16x32_bf16(af, bf, acc[n], 0, 0, 0);
            }
        }

        const int crow = row0 + wv * 16 + (ln >> 4) * 4;
        const int ccol = ln & 15;
#pragma unroll
        for (int n = 0; n < 16; ++n) {
#pragma unroll
            for (int reg = 0; reg < 4; ++reg) {
                const int r = crow + reg;
                if (r < N) sup[(size_t)r * D + n * 16 + ccol] = f2bf_rne(acc[n][reg]);
            }
        }
    } else {
        // ---------------- bucket scatter ----------------
        const int e0 = (bid / 5) * CHUNK;
        const int e1 = min(e0 + CHUNK, E);

        for (int i = tid; i < 1024; i += 256) sm.cur[i] = 0;
        __syncthreads();

        for (int e = e0 + tid; e < e1; e += 256)
            atomicAdd(&sm.cur[edge_row[e] >> BSHIFT], 1);
        __syncthreads();

        for (int b = tid; b < NB; b += 256) {
            const int c = sm.cur[b];
            sm.cur[b] = (c > 0) ? atomicAdd(&bcursor[b], c) : 0;
        }
        __syncthreads();

        for (int e = e0 + tid; e < e1; e += 256) {
            const int r = edge_row[e];
            const int b = r >> BSHIFT;
            const int pos = atomicAdd(&sm.cur[b], 1);
            const unsigned long long pk =
                ((unsigned long long)(uint)f2bf_rne(
                     __builtin_nontemporal_load(edge_val + e)) << 48) |
                ((unsigned long long)(uint)
                     __builtin_nontemporal_load(edge_col + e) << 17) | (uint)r;
            ebuck[pos] = pk;
        }
    }
}

// packed (col, val): low 32 = col, high 32 = val bits
__device__ inline long long pack_cv(int c, float v) {
    return (long long)(((unsigned long long)__builtin_bit_cast(uint, v) << 32) |
                       (uint)c);
}

// ===========================================================================
// Pass B: fine scatter, row_start fused (proven r8/r10/r12).
// Pass-1 ebuck read plain (warms L2 for pass 2); pass-2 read nt (last use).
// ===========================================================================
__global__ __launch_bounds__(256) void fine_scatter(
        const unsigned long long* __restrict__ ebuck,
        const int* __restrict__ bstart,
        long long* __restrict__ epair,
        int* __restrict__ row_start, int N) {
    __shared__ int cnt[BROWS];
    __shared__ int cur[BROWS];
    const int tid = threadIdx.x;
    const int r0  = blockIdx.x << BSHIFT;
    const int s   = bstart[blockIdx.x];
    const int e   = bstart[blockIdx.x + 1];

    if (tid < BROWS) cnt[tid] = 0;
    __syncthreads();

    for (int i = s + tid; i < e; i += 256)
        atomicAdd(&cnt[(int)(ebuck[i] & 0x1FFFFu) - r0], 1);
    __syncthreads();

    if (tid < BROWS) cur[tid] = cnt[tid];
    __syncthreads();
#pragma unroll
    for (int off = 1; off < BROWS; off <<= 1) {
        const int t = (tid < BROWS && tid >= off) ? cur[tid - off] : 0;
        __syncthreads();
        if (tid < BROWS) cur[tid] += t;
        __syncthreads();
    }
    if (tid < BROWS) {
        const int rs = s + cur[tid] - cnt[tid];  // exclusive
        cur[tid] = rs;                           // becomes cursor
        const int row = r0 + tid;
        if (row < N) row_start[row] = rs;
    }
    __syncthreads();

    for (int i = s + tid; i < e; i += 256) {
        const unsigned long long pk =
            __builtin_nontemporal_load(ebuck + i);  // last use of ebuck
        const int  r  = (int)(pk & 0x1FFFFu) - r0;
        const int  c  = (int)((pk >> 17) & 0x1FFFFu);
        const float v = __builtin_bit_cast(float, (uint)(pk >> 48) << 16);
        const int pos = atomicAdd(&cur[r], 1);
        epair[pos] = pack_cv(c, v);
    }
}

// ===========================================================================
// accumulate: one wave per row; 16 gathers in flight (proven r11/r12, 217 µs).
// ===========================================================================
__global__ __launch_bounds__(256) void accumulate(const ushort* __restrict__ sup,
                                                  const int* __restrict__ row_start,
                                                  const long long* __restrict__ epair,
                                                  const float* __restrict__ bias,
                                                  float* __restrict__ out, int N) {
    const int row = blockIdx.x * 4 + (threadIdx.x >> 6);
    if (row >= N) return;
    const int lane = threadIdx.x & 63;
    const int lofs = lane * 4;  // ushort offset within a sup row

    const int s = row_start[row];
    const int e = row_start[row + 1];

    f32x4 a[8];
    a[0] = *(const f32x4*)(bias + lofs);
#pragma unroll
    for (int q = 1; q < 8; ++q) a[q] = (f32x4){0.f, 0.f, 0.f, 0.f};

    for (int base = s; base < e; base += 64) {
        const int idx = base + lane;
        long long pk = 0;
        if (idx < e) pk = __builtin_nontemporal_load(epair + idx);
        const int   c = (int)(uint)pk;
        const float v = __builtin_bit_cast(float, (uint)((unsigned long long)pk >> 32));
        const int n = min(64, e - base);
        int j = 0;
        for (; j + 15 < n; j += 16) {
            int   cq[16];
            float vq[16];
            uint2 uq[16];
#pragma unroll
            for (int q = 0; q < 16; ++q) {
                cq[q] = __shfl(c, j + q);
                vq[q] = __shfl(v, j + q);
            }
#pragma unroll
            for (int q = 0; q < 16; ++q)
                uq[q] = *(const uint2*)(sup + ((uint)cq[q] << 8) + lofs);
#pragma unroll
            for (int q = 0; q < 16; ++q) {
                const float f0 = __builtin_bit_cast(float, uq[q].x << 16);
                const float f1 = __builtin_bit_cast(float, uq[q].x & 0xFFFF0000u);
                const float f2 = __builtin_bit_cast(float, uq[q].y << 16);
                const float f3 = __builtin_bit_cast(float, uq[q].y & 0xFFFF0000u);
                a[q & 7][0] = fmaf(vq[q], f0, a[q & 7][0]);
                a[q & 7][1] = fmaf(vq[q], f1, a[q & 7][1]);
                a[q & 7][2] = fmaf(vq[q], f2, a[q & 7][2]);
                a[q & 7][3] = fmaf(vq[q], f3, a[q & 7][3]);
            }
        }
        for (; j + 7 < n; j += 8) {
            int   cq[8];
            float vq[8];
            uint2 uq[8];
#pragma unroll
            for (int q = 0; q < 8; ++q) {
                cq[q] = __shfl(c, j + q);
                vq[q] = __shfl(v, j + q);
            }
#pragma unroll
            for (int q = 0; q < 8; ++q)
                uq[q] = *(const uint2*)(sup + ((uint)cq[q] << 8) + lofs);
#pragma unroll
            for (int q = 0; q < 8; ++q) {
                const float f0 = __builtin_bit_cast(float, uq[q].x << 16);
                const float f1 = __builtin_bit_cast(float, uq[q].x & 0xFFFF0000u);
                const float f2 = __builtin_bit_cast(float, uq[q].y << 16);
                const float f3 = __builtin_bit_cast(float, uq[q].y & 0xFFFF0000u);
                a[q][0] = fmaf(vq[q], f0, a[q][0]);
                a[q][1] = fmaf(vq[q], f1, a[q][1]);
                a[q][2] = fmaf(vq[q], f2, a[q][2]);
                a[q][3] = fmaf(vq[q], f3, a[q][3]);
            }
        }
        for (; j < n; ++j) {
            const int   c0 = __shfl(c, j);
            const float v0 = __shfl(v, j);
            const uint2 u  = *(const uint2*)(sup + ((uint)c0 << 8) + lofs);
            const float f0 = __builtin_bit_cast(float, u.x << 16);
            const float f1 = __builtin_bit_cast(float, u.x & 0xFFFF0000u);
            const float f2 = __builtin_bit_cast(float, u.y << 16);
            const float f3 = __builtin_bit_cast(float, u.y & 0xFFFF0000u);
            a[0][0] = fmaf(v0, f0, a[0][0]);
            a[0][1] = fmaf(v0, f1, a[0][1]);
            a[0][2] = fmaf(v0, f2, a[0][2]);
            a[0][3] = fmaf(v0, f3, a[0][3]);
        }
    }
#pragma unroll
    for (int q = 1; q < 8; ++q) {
        a[0][0] += a[q][0]; a[0][1] += a[q][1];
        a[0][2] += a[q][2]; a[0][3] += a[q][3];
    }
    __builtin_nontemporal_store(a[0], (f32x4*)(out + (size_t)row * D + lofs));
}

// ===========================================================================
extern "C" void kernel_launch(void* const* d_in, const int* in_sizes, int n_in,
                              void* d_out, int out_size, void* d_ws, size_t ws_size,
                              hipStream_t stream) {
    const float* x        = (const float*)d_in[0];
    const float* edge_val = (const float*)d_in[1];
    const float* weight   = (const float*)d_in[2];
    const float* bias     = (const float*)d_in[3];
    const int*   edge_row = (const int*)d_in[4];
    const int*   edge_col = (const int*)d_in[5];
    float*       out      = (float*)d_out;

    const int N = in_sizes[0] / D;   // 100000
    const int E = in_sizes[1];       // 3200000

    char* ws = (char*)d_ws;
    size_t off = 0;
    auto carve = [&](size_t bytes) -> char* {
        char* p = ws + off;
        off = (off + bytes + 255) & ~(size_t)255;
        return p;
    };

    const int NB = (N + BROWS - 1) / BROWS;  // 782 buckets

    ushort* sup = (ushort*)carve((size_t)N * D * sizeof(ushort));   // 51.2 MB
    ushort* wt  = (ushort*)carve((size_t)D * D * sizeof(ushort));   // 128 KB
    unsigned long long* ebuck =
        (unsigned long long*)carve((size_t)E * sizeof(unsigned long long));  // 25.6 MB
    long long* epair = (long long*)carve((size_t)E * sizeof(long long));     // 25.6 MB
    int* row_start = (int*)carve((size_t)(N + 1) * sizeof(int));
    int* bcnt      = (int*)carve((size_t)NB * sizeof(int));
    int* bstart    = (int*)carve((size_t)(NB + 1) * sizeof(int));
    int* bcursor   = (int*)carve((size_t)NB * sizeof(int));

    const int ngemm  = (N + 63) / 64;            // 1563
    const int nchunk = (E + CHUNK - 1) / CHUNK;  // 391
    const int ngrid  = 5 * nchunk;               // 1955: 391 scatter + 1564 gemm

    // 1) prep: wt conversion + bcnt zero
    prep<<<(D * D + NB + 255) / 256, 256, 0, stream>>>(weight, wt, bcnt, NB);

    // 2) bucket hist + scan
    bucket_hist<<<nchunk, 256, 0, stream>>>(edge_row, bcnt, E, NB);
    bucket_scan<<<1, 512, 0, stream>>>(bcnt, bstart, bcursor, row_start, NB, N, E);

    // 3) fused interleaved: GEMM + coarse bucket scatter
    gemm_scatter<<<ngrid, 256, 0, stream>>>(
        x, wt, sup, N, ngemm, edge_row, edge_col, edge_val, bcursor, ebuck, E, NB,
        nchunk);

    // 4) fine scatter (row-sorted epair + row_start)
    fine_scatter<<<NB, 256, 0, stream>>>(ebuck, bstart, epair, row_start, N);

    // 5) gather-accumulate (bias folded in)
    accumulate<<<(N + 3) / 4, 256, 0, stream>>>(sup, row_start, epair, bias, out, N);
}

// Round 15
// 397.828 us; speedup vs baseline: 1.0691x; 1.0691x over previous
//
#include <hip/hip_runtime.h>

#define D 256          // D_IN == D_OUT == 256
#define BSHIFT 6       // 64 rows per bucket
#define BROWS 64
#define CHUNK 8192     // edges per bucket_hist / bucket_scatter block
// NB = ceil(100000/64) = 1563; kernels assume NB <= 2048

typedef __attribute__((ext_vector_type(8))) short bf16x8;  // 8 bf16 in 4 VGPRs
typedef __attribute__((ext_vector_type(4))) float f32x4;

__device__ inline ushort f2bf_rne(float f) {  // fp32 -> bf16, round-to-nearest-even
    uint u = __builtin_bit_cast(uint, f);
    return (ushort)((u + 0x7FFFu + ((u >> 16) & 1u)) >> 16);
}

// ===========================================================================
// prep: conv_wt (wt[n][k] = bf16(W[k][n])) + zero bcnt, fused by idx range
// ===========================================================================
__global__ __launch_bounds__(256) void prep(const float* __restrict__ w,
                                            ushort* __restrict__ wt,
                                            int* __restrict__ bcnt, int NB) {
    const int idx = blockIdx.x * 256 + threadIdx.x;
    if (idx < D * D) {
        const int n = idx >> 8, k = idx & 255;
        wt[n * 256 + k] = f2bf_rne(w[k * 256 + n]);
    } else if (idx - D * D < NB) {
        bcnt[idx - D * D] = 0;
    }
}

// ===========================================================================
// Bucket-level histogram (BSHIFT=6 variant proven r13).
// ===========================================================================
__global__ __launch_bounds__(256) void bucket_hist(const int* __restrict__ edge_row,
                                                   int* __restrict__ bcnt,
                                                   int E, int NB) {
    __shared__ int bh[2048];
    const int tid = threadIdx.x;
    for (int i = tid; i < 2048; i += 256) bh[i] = 0;
    __syncthreads();

    const int e0 = blockIdx.x * CHUNK;
    const int e1 = min(e0 + CHUNK, E);
    for (int i = e0 + tid * 4; i < e1; i += 1024) {
        if (i + 3 < e1) {
            const int4 r = *(const int4*)(edge_row + i);
            atomicAdd(&bh[r.x >> BSHIFT], 1);
            atomicAdd(&bh[r.y >> BSHIFT], 1);
            atomicAdd(&bh[r.z >> BSHIFT], 1);
            atomicAdd(&bh[r.w >> BSHIFT], 1);
        } else {
            for (int j = i; j < e1; ++j) atomicAdd(&bh[edge_row[j] >> BSHIFT], 1);
        }
    }
    __syncthreads();

    for (int b = tid; b < NB; b += 256) {
        const int c = bh[b];
        if (c) atomicAdd(&bcnt[b], c);
    }
}

// ===========================================================================
// Single-block exclusive scan over NB <= 2048 bucket counts (proven r13),
// plus the row_start[N] = E sentinel accumulate needs (r12).
// ===========================================================================
__global__ __launch_bounds__(512) void bucket_scan(const int* __restrict__ bcnt,
                                                   int* __restrict__ bstart,
                                                   int* __restrict__ bcursor,
                                                   int* __restrict__ row_start,
                                                   int NB, int N, int E) {
    __shared__ int psum[512];
    const int tid = threadIdx.x;
    int v[4];
    int s = 0;
#pragma unroll
    for (int k = 0; k < 4; ++k) {
        const int i = tid * 4 + k;
        v[k] = (i < NB) ? bcnt[i] : 0;
        s += v[k];
    }
    psum[tid] = s;
    __syncthreads();
#pragma unroll
    for (int off = 1; off < 512; off <<= 1) {
        const int t = (tid >= off) ? psum[tid - off] : 0;
        __syncthreads();
        psum[tid] += t;
        __syncthreads();
    }
    int run = psum[tid] - s;  // exclusive prefix of this thread's 4-group
#pragma unroll
    for (int k = 0; k < 4; ++k) {
        const int i = tid * 4 + k;
        if (i < NB) { bstart[i] = run; bcursor[i] = run; }
        run += v[k];
    }
    if (tid == 0) { bstart[NB] = E; row_start[N] = E; }
}

// ===========================================================================
// gemm_scatter: gemm + bucket scatter, interleaved roles (r12 structure,
// BSHIFT=6 scatter with cur[2048] proven r13).  Plain loads (r14 nt regressed).
// ===========================================================================
union SMemGS {
    ushort As[64 * 256];  // 32 KB
    int    cur[2048];     //  8 KB
};

__global__ __launch_bounds__(256) void gemm_scatter(
        const float* __restrict__ x, const ushort* __restrict__ wt,
        ushort* __restrict__ sup, int N, int ngemm,
        const int* __restrict__ edge_row, const int* __restrict__ edge_col,
        const float* __restrict__ edge_val, int* __restrict__ bcursor,
        unsigned long long* __restrict__ ebuck, int E, int NB, int nchunk) {
    __shared__ SMemGS sm;
    const int tid = threadIdx.x;
    const int bid = blockIdx.x;

    const bool is_scatter = ((bid % 5) == 4) && (bid / 5 < nchunk);

    if (!is_scatter) {
        // ---------------- GEMM ----------------
        const int gb = bid - (bid + 1) / 5;  // gemm block index
        if (gb >= ngemm) return;
        const int wv  = tid >> 6;
        const int ln  = tid & 63;
        const int row0 = gb * 64;

        for (int i = tid; i < 64 * 64; i += 256) {
            const int r = i >> 6, c = i & 63;
            int gr = row0 + r;
            if (gr >= N) gr = N - 1;
            const float4 xv = *(const float4*)(x + (size_t)gr * D + c * 4);
            ushort4 b;
            b.x = f2bf_rne(xv.x); b.y = f2bf_rne(xv.y);
            b.z = f2bf_rne(xv.z); b.w = f2bf_rne(xv.w);
            const int byte = (r * 512 + c * 8) ^ ((r & 7) << 4);
            *(ushort4*)((char*)sm.As + byte) = b;
        }
        __syncthreads();

        f32x4 acc[16];
#pragma unroll
        for (int n = 0; n < 16; ++n) acc[n] = (f32x4){0.f, 0.f, 0.f, 0.f};

        const int arow = wv * 16 + (ln & 15);
        const int ksub = (ln >> 4) * 16;
        const ushort* wbase = wt + (ln & 15) * 256;

#pragma unroll
        for (int kk = 0; kk < 8; ++kk) {
            const int abyte = (arow * 512 + kk * 64 + ksub) ^ ((arow & 7) << 4);
            const bf16x8 af = *(const bf16x8*)((const char*)sm.As + abyte);
            const ushort* wp = wbase + kk * 32 + (ln >> 4) * 8;
#pragma unroll
            for (int n = 0; n < 16; ++n) {
                const bf16x8 bf = *(const bf16x8*)(wp + n * 16 * 256);
                acc[n] = __builtin_amdgcn_mfma_f32_16x16x32_bf16(af, bf, acc[n], 0, 0, 0);
            }
        }

        const int crow = row0 + wv * 16 + (ln >> 4) * 4;
        const int ccol = ln & 15;
#pragma unroll
        for (int n = 0; n < 16; ++n) {
#pragma unroll
            for (int reg = 0; reg < 4; ++reg) {
                const int r = crow + reg;
                if (r < N) sup[(size_t)r * D + n * 16 + ccol] = f2bf_rne(acc[n][reg]);
            }
        }
    } else {
        // ---------------- bucket scatter ----------------
        const int e0 = (bid / 5) * CHUNK;
        const int e1 = min(e0 + CHUNK, E);

        for (int i = tid; i < 2048; i += 256) sm.cur[i] = 0;
        __syncthreads();

        for (int e = e0 + tid; e < e1; e += 256)
            atomicAdd(&sm.cur[edge_row[e] >> BSHIFT], 1);
        __syncthreads();

        for (int b = tid; b < NB; b += 256) {
            const int c = sm.cur[b];
            sm.cur[b] = (c > 0) ? atomicAdd(&bcursor[b], c) : 0;
        }
        __syncthreads();

        for (int e = e0 + tid; e < e1; e += 256) {
            const int r = edge_row[e];
            const int b = r >> BSHIFT;
            const int pos = atomicAdd(&sm.cur[b], 1);
            const unsigned long long pk =
                ((unsigned long long)(uint)f2bf_rne(edge_val[e]) << 48) |
                ((unsigned long long)(uint)edge_col[e] << 17) | (uint)r;
            ebuck[pos] = pk;
        }
    }
}

// packed (col, val): low 32 = col, high 32 = val bits
__device__ inline long long pack_cv(int c, float v) {
    return (long long)(((unsigned long long)__builtin_bit_cast(uint, v) << 32) |
                       (uint)c);
}

// ===========================================================================
// Fine scatter, row_start fused (r12-proven structure, 64-row buckets):
// 1563 blocks (2x of r12) -> half the per-block serial sort work, better
// load balance and latency hiding for the atomic/barrier-bound phases.
// ===========================================================================
__global__ __launch_bounds__(256) void fine_scatter(
        const unsigned long long* __restrict__ ebuck,
        const int* __restrict__ bstart,
        long long* __restrict__ epair,
        int* __restrict__ row_start, int N) {
    __shared__ int cnt[BROWS];
    __shared__ int cur[BROWS];
    const int tid = threadIdx.x;
    const int r0  = blockIdx.x << BSHIFT;
    const int s   = bstart[blockIdx.x];
    const int e   = bstart[blockIdx.x + 1];

    if (tid < BROWS) cnt[tid] = 0;
    __syncthreads();

    // pass 1: per-row count
    for (int i = s + tid; i < e; i += 256)
        atomicAdd(&cnt[(int)(ebuck[i] & 0x1FFFFu) - r0], 1);
    __syncthreads();

    // block scan of 64 counters (Hillis-Steele)
    if (tid < BROWS) cur[tid] = cnt[tid];
    __syncthreads();
#pragma unroll
    for (int off = 1; off < BROWS; off <<= 1) {
        const int t = (tid < BROWS && tid >= off) ? cur[tid - off] : 0;
        __syncthreads();
        if (tid < BROWS) cur[tid] += t;
        __syncthreads();
    }
    if (tid < BROWS) {
        const int rs = s + cur[tid] - cnt[tid];  // exclusive
        cur[tid] = rs;                           // becomes cursor
        const int row = r0 + tid;
        if (row < N) row_start[row] = rs;
    }
    __syncthreads();

    // pass 2: scatter into the row-sorted segment
    for (int i = s + tid; i < e; i += 256) {
        const unsigned long long pk = ebuck[i];
        const int  r  = (int)(pk & 0x1FFFFu) - r0;
        const int  c  = (int)((pk >> 17) & 0x1FFFFu);
        const float v = __builtin_bit_cast(float, (uint)(pk >> 48) << 16);
        const int pos = atomicAdd(&cur[r], 1);
        epair[pos] = pack_cv(c, v);
    }
}

// ===========================================================================
// accumulate: one wave per row; 16 gathers in flight (proven r11/r12, 217 µs).
// ===========================================================================
__global__ __launch_bounds__(256) void accumulate(const ushort* __restrict__ sup,
                                                  const int* __restrict__ row_start,
                                                  const long long* __restrict__ epair,
                                                  const float* __restrict__ bias,
                                                  float* __restrict__ out, int N) {
    const int row = blockIdx.x * 4 + (threadIdx.x >> 6);
    if (row >= N) return;
    const int lane = threadIdx.x & 63;
    const int lofs = lane * 4;  // ushort offset within a sup row

    const int s = row_start[row];
    const int e = row_start[row + 1];

    f32x4 a[8];
    a[0] = *(const f32x4*)(bias + lofs);
#pragma unroll
    for (int q = 1; q < 8; ++q) a[q] = (f32x4){0.f, 0.f, 0.f, 0.f};

    for (int base = s; base < e; base += 64) {
        const int idx = base + lane;
        long long pk = 0;
        if (idx < e) pk = __builtin_nontemporal_load(epair + idx);
        const int   c = (int)(uint)pk;
        const float v = __builtin_bit_cast(float, (uint)((unsigned long long)pk >> 32));
        const int n = min(64, e - base);
        int j = 0;
        for (; j + 15 < n; j += 16) {
            int   cq[16];
            float vq[16];
            uint2 uq[16];
#pragma unroll
            for (int q = 0; q < 16; ++q) {
                cq[q] = __shfl(c, j + q);
                vq[q] = __shfl(v, j + q);
            }
#pragma unroll
            for (int q = 0; q < 16; ++q)
                uq[q] = *(const uint2*)(sup + ((uint)cq[q] << 8) + lofs);
#pragma unroll
            for (int q = 0; q < 16; ++q) {
                const float f0 = __builtin_bit_cast(float, uq[q].x << 16);
                const float f1 = __builtin_bit_cast(float, uq[q].x & 0xFFFF0000u);
                const float f2 = __builtin_bit_cast(float, uq[q].y << 16);
                const float f3 = __builtin_bit_cast(float, uq[q].y & 0xFFFF0000u);
                a[q & 7][0] = fmaf(vq[q], f0, a[q & 7][0]);
                a[q & 7][1] = fmaf(vq[q], f1, a[q & 7][1]);
                a[q & 7][2] = fmaf(vq[q], f2, a[q & 7][2]);
                a[q & 7][3] = fmaf(vq[q], f3, a[q & 7][3]);
            }
        }
        for (; j + 7 < n; j += 8) {
            int   cq[8];
            float vq[8];
            uint2 uq[8];
#pragma unroll
            for (int q = 0; q < 8; ++q) {
                cq[q] = __shfl(c, j + q);
                vq[q] = __shfl(v, j + q);
            }
#pragma unroll
            for (int q = 0; q < 8; ++q)
                uq[q] = *(const uint2*)(sup + ((uint)cq[q] << 8) + lofs);
#pragma unroll
            for (int q = 0; q < 8; ++q) {
                const float f0 = __builtin_bit_cast(float, uq[q].x << 16);
                const float f1 = __builtin_bit_cast(float, uq[q].x & 0xFFFF0000u);
                const float f2 = __builtin_bit_cast(float, uq[q].y << 16);
                const float f3 = __builtin_bit_cast(float, uq[q].y & 0xFFFF0000u);
                a[q][0] = fmaf(vq[q], f0, a[q][0]);
                a[q][1] = fmaf(vq[q], f1, a[q][1]);
                a[q][2] = fmaf(vq[q], f2, a[q][2]);
                a[q][3] = fmaf(vq[q], f3, a[q][3]);
            }
        }
        for (; j < n; ++j) {
            const int   c0 = __shfl(c, j);
            const float v0 = __shfl(v, j);
            const uint2 u  = *(const uint2*)(sup + ((uint)c0 << 8) + lofs);
            const float f0 = __builtin_bit_cast(float, u.x << 16);
            const float f1 = __builtin_bit_cast(float, u.x & 0xFFFF0000u);
            const float f2 = __builtin_bit_cast(float, u.y << 16);
            const float f3 = __builtin_bit_cast(float, u.y & 0xFFFF0000u);
            a[0][0] = fmaf(v0, f0, a[0][0]);
            a[0][1] = fmaf(v0, f1, a[0][1]);
            a[0][2] = fmaf(v0, f2, a[0][2]);
            a[0][3] = fmaf(v0, f3, a[0][3]);
        }
    }
#pragma unroll
    for (int q = 1; q < 8; ++q) {
        a[0][0] += a[q][0]; a[0][1] += a[q][1];
        a[0][2] += a[q][2]; a[0][3] += a[q][3];
    }
    __builtin_nontemporal_store(a[0], (f32x4*)(out + (size_t)row * D + lofs));
}

// ===========================================================================
extern "C" void kernel_launch(void* const* d_in, const int* in_sizes, int n_in,
                              void* d_out, int out_size, void* d_ws, size_t ws_size,
                              hipStream_t stream) {
    const float* x        = (const float*)d_in[0];
    const float* edge_val = (const float*)d_in[1];
    const float* weight   = (const float*)d_in[2];
    const float* bias     = (const float*)d_in[3];
    const int*   edge_row = (const int*)d_in[4];
    const int*   edge_col = (const int*)d_in[5];
    float*       out      = (float*)d_out;

    const int N = in_sizes[0] / D;   // 100000
    const int E = in_sizes[1];       // 3200000

    char* ws = (char*)d_ws;
    size_t off = 0;
    auto carve = [&](size_t bytes) -> char* {
        char* p = ws + off;
        off = (off + bytes + 255) & ~(size_t)255;
        return p;
    };

    const int NB = (N + BROWS - 1) / BROWS;  // 1563 buckets

    ushort* sup = (ushort*)carve((size_t)N * D * sizeof(ushort));   // 51.2 MB
    ushort* wt  = (ushort*)carve((size_t)D * D * sizeof(ushort));   // 128 KB
    unsigned long long* ebuck =
        (unsigned long long*)carve((size_t)E * sizeof(unsigned long long));  // 25.6 MB
    long long* epair = (long long*)carve((size_t)E * sizeof(long long));     // 25.6 MB
    int* row_start = (int*)carve((size_t)(N + 1) * sizeof(int));
    int* bcnt      = (int*)carve((size_t)NB * sizeof(int));
    int* bstart    = (int*)carve((size_t)(NB + 1) * sizeof(int));
    int* bcursor   = (int*)carve((size_t)NB * sizeof(int));

    const int ngemm  = (N + 63) / 64;            // 1563
    const int nchunk = (E + CHUNK - 1) / CHUNK;  // 391
    const int ngrid  = 5 * nchunk;               // 1955: 391 scatter + 1564 gemm

    // 1) prep: wt conversion + bcnt zero
    prep<<<(D * D + NB + 255) / 256, 256, 0, stream>>>(weight, wt, bcnt, NB);

    // 2) bucket hist + scan
    bucket_hist<<<nchunk, 256, 0, stream>>>(edge_row, bcnt, E, NB);
    bucket_scan<<<1, 512, 0, stream>>>(bcnt, bstart, bcursor, row_start, NB, N, E);

    // 3) fused interleaved: GEMM + coarse bucket scatter
    gemm_scatter<<<ngrid, 256, 0, stream>>>(
        x, wt, sup, N, ngemm, edge_row, edge_col, edge_val, bcursor, ebuck, E, NB,
        nchunk);

    // 4) fine scatter (row-sorted epair + row_start), 64-row buckets
    fine_scatter<<<NB, 256, 0, stream>>>(ebuck, bstart, epair, row_start, N);

    // 5) gather-accumulate (bias folded in)
    accumulate<<<(N + 3) / 4, 256, 0, stream>>>(sup, row_start, epair, bias, out, N);
}